// Round 3
// baseline (122.669 us; speedup 1.0000x reference)
//
#include <hip/hip_runtime.h>
#include <stdint.h>

// BCM_Linear: out = x @ W^T, W[o,k] = w[o>>6, k>>6, (o-k)&63]  (1024x1024)
// M=32768, N=1024, K=1024. bf16 MFMA compute, fp32 in/out.
// 256x256 8-phase template; A-staging FUSES fp32->bf16 conversion
// (reg-stage: global fp32 -> cvt -> swizzled ds_write), B via pre-swizzled
// bf16 Wb + global_load_lds. T1+T2+T3+T4+T5.

#define NTOK 32768
#define NCH  1024
#define BK   64
#define NKT  (NCH / BK)   // 16

typedef short bf16x8 __attribute__((ext_vector_type(8)));
typedef float f32x4  __attribute__((ext_vector_type(4)));
typedef unsigned short u16x8 __attribute__((ext_vector_type(8)));

static __device__ __forceinline__ unsigned short f2bf(float f) {
    unsigned int u = __float_as_uint(f);
    u += 0x7FFFu + ((u >> 16) & 1u);
    return (unsigned short)(u >> 16);
}

static __device__ __forceinline__ u16x8 pack8(float4 a, float4 b) {
    u16x8 v;
    v[0]=f2bf(a.x); v[1]=f2bf(a.y); v[2]=f2bf(a.z); v[3]=f2bf(a.w);
    v[4]=f2bf(b.x); v[5]=f2bf(b.y); v[6]=f2bf(b.z); v[7]=f2bf(b.w);
    return v;
}

#define GLOAD16(gp, lp)                                                          \
    __builtin_amdgcn_global_load_lds(                                            \
        (const __attribute__((address_space(1))) unsigned int*)(gp),             \
        (__attribute__((address_space(3))) unsigned int*)(lp), 16, 0, 0)

// ---------------- kernel 1: circulant w -> dense bf16 W (N x K), pre-swizzled ----------------
__global__ void build_w_kernel(const float* __restrict__ w, unsigned short* __restrict__ Wb) {
    int i = blockIdx.x * blockDim.x + threadIdx.x;   // 0 .. 1024*128-1
    int o = i >> 7;
    int j = i & 127;                // 16B-block index within 2048B row
    int r = o >> 6;
    int q = j >> 3;
    const float* wrow = w + ((r * 16 + q) << 6);
    int k0 = j << 3;
    u16x8 v;
#pragma unroll
    for (int e = 0; e < 8; ++e) v[e] = f2bf(wrow[(o - (k0 + e)) & 63]);
    int js = (j & ~7) | ((j & 7) ^ (o & 7));   // st-swizzle within each 128B chunk
    *(u16x8*)(Wb + (((size_t)o) << 10) + (js << 3)) = v;
}

// ---------------- kernel 2: 256x256 8-phase GEMM with fused A-conversion ----------------
#define PHASE_BAR() __builtin_amdgcn_s_barrier()
#define LGKM0() asm volatile("s_waitcnt lgkmcnt(0)" ::: "memory")
#define VMCNT(n) asm volatile("s_waitcnt vmcnt(" #n ")" ::: "memory")
#define CFENCE() asm volatile("" ::: "memory")
#define SETPRIO(n) __builtin_amdgcn_s_setprio(n)
#define MFMA4(d, av, bv) d = __builtin_amdgcn_mfma_f32_16x16x32_bf16(av, bv, d, 0, 0, 0)

// B staging: one half-tile (128 rows x 64 cols bf16 = 16 KB), 2 gload16/thread.
#define STAGE_HALF_B(ldsbuf, t, h) do {                                          \
    const char* _s = srcB + (((size_t)(h)) << 18) + (((size_t)(t)) << 7);        \
    char* _d = (ldsbuf) + ((h) << 14) + (wv << 10);                              \
    GLOAD16(_s, _d);                                                             \
    GLOAD16(_s + ((size_t)64 << 11), _d + 8192);                                 \
} while (0)

// A issue: 8x global_load_dwordx4 fp32 (16 floats/thread/half x 2 halves... 16 total floats
// per half? -> 16 floats per half-tile row-piece; 2 halves = 32 floats? No:
// thread covers 16 consecutive K-floats in ONE row per half: 4 float4 per half.
#define ISSUE_A(t) do {                                                          \
    const float4* _p0 = (const float4*)(pA + ((t) << 6));                        \
    const float4* _p1 = (const float4*)(pA + ((t) << 6) + (128 << 10));          \
    areg[0]=_p0[0]; areg[1]=_p0[1]; areg[2]=_p0[2]; areg[3]=_p0[3];              \
    areg[4]=_p1[0]; areg[5]=_p1[1]; areg[6]=_p1[2]; areg[7]=_p1[3];              \
    CFENCE();                                                                    \
} while (0)

// A write: cvt 32 floats -> 4x swizzled ds_write_b128 (2 per half-tile).
#define WRITE_A(Abuf) do {                                                       \
    u16x8 _w0 = pack8(areg[0], areg[1]);                                         \
    u16x8 _w1 = pack8(areg[2], areg[3]);                                         \
    u16x8 _w2 = pack8(areg[4], areg[5]);                                         \
    u16x8 _w3 = pack8(areg[6], areg[7]);                                         \
    *(u16x8*)((Abuf) + aw0)         = _w0;                                       \
    *(u16x8*)((Abuf) + aw1)         = _w1;                                       \
    *(u16x8*)((Abuf) + aw0 + 16384) = _w2;                                       \
    *(u16x8*)((Abuf) + aw1 + 16384) = _w3;                                       \
    CFENCE();                                                                    \
} while (0)

#define NOHOOK ((void)0)

// One K-tile = 4 phases. H3 runs in P3 (B gload + vmcnt + A cvt/ds_write);
// H4 runs in P4 (issue next-next A-regs).
#define KTILE(Abuf, Bbuf, H3, H4)                                                \
  do {                                                                           \
    bf16x8 afr[4][2], bfr[4][2];                                                 \
    _Pragma("unroll") for (int m = 0; m < 4; ++m)                                \
      _Pragma("unroll") for (int ks = 0; ks < 2; ++ks)                           \
        afr[m][ks] = *(const bf16x8*)((Abuf) + a_off[ks] + m * 2048);            \
    _Pragma("unroll") for (int n = 0; n < 2; ++n)                                \
      _Pragma("unroll") for (int ks = 0; ks < 2; ++ks)                           \
        bfr[n][ks] = *(const bf16x8*)((Bbuf) + b_off[ks] + n * 2048);            \
    PHASE_BAR(); LGKM0();                                                        \
    SETPRIO(1);                                                                  \
    _Pragma("unroll") for (int m = 0; m < 4; ++m)                                \
      _Pragma("unroll") for (int n = 0; n < 2; ++n) {                            \
        MFMA4(acc[m][n], afr[m][0], bfr[n][0]);                                  \
        MFMA4(acc[m][n], afr[m][1], bfr[n][1]);                                  \
      }                                                                          \
    SETPRIO(0); PHASE_BAR();                                                     \
    /* P2 */                                                                     \
    _Pragma("unroll") for (int n = 2; n < 4; ++n)                                \
      _Pragma("unroll") for (int ks = 0; ks < 2; ++ks)                           \
        bfr[n][ks] = *(const bf16x8*)((Bbuf) + b_off[ks] + n * 2048);            \
    PHASE_BAR(); LGKM0();                                                        \
    SETPRIO(1);                                                                  \
    _Pragma("unroll") for (int m = 0; m < 4; ++m)                                \
      _Pragma("unroll") for (int n = 2; n < 4; ++n) {                            \
        MFMA4(acc[m][n], afr[m][0], bfr[n][0]);                                  \
        MFMA4(acc[m][n], afr[m][1], bfr[n][1]);                                  \
      }                                                                          \
    SETPRIO(0); PHASE_BAR();                                                     \
    /* P3 */                                                                     \
    _Pragma("unroll") for (int m = 0; m < 4; ++m)                                \
      _Pragma("unroll") for (int ks = 0; ks < 2; ++ks)                           \
        afr[m][ks] = *(const bf16x8*)((Abuf) + a_off[ks] + (m + 4) * 2048);      \
    H3;                                                                          \
    PHASE_BAR(); LGKM0();                                                        \
    SETPRIO(1);                                                                  \
    _Pragma("unroll") for (int m = 0; m < 4; ++m)                                \
      _Pragma("unroll") for (int n = 0; n < 2; ++n) {                            \
        MFMA4(acc[m + 4][n], afr[m][0], bfr[n][0]);                              \
        MFMA4(acc[m + 4][n], afr[m][1], bfr[n][1]);                              \
      }                                                                          \
    SETPRIO(0); PHASE_BAR();                                                     \
    /* P4 */                                                                     \
    H4;                                                                          \
    PHASE_BAR();                                                                 \
    SETPRIO(1);                                                                  \
    _Pragma("unroll") for (int m = 0; m < 4; ++m)                                \
      _Pragma("unroll") for (int n = 2; n < 4; ++n) {                            \
        MFMA4(acc[m + 4][n], afr[m][0], bfr[n][0]);                              \
        MFMA4(acc[m + 4][n], afr[m][1], bfr[n][1]);                              \
      }                                                                          \
    SETPRIO(0); PHASE_BAR();                                                     \
  } while (0)

__global__ void __launch_bounds__(512, 1) gemm8_kernel(const float* __restrict__ X,
                                                       const unsigned short* __restrict__ B,
                                                       float* __restrict__ C) {
    __shared__ __align__(16) char lds[131072];
    char* As0 = lds;                 // A buf: 256 rows x 128 B (32 KB)
    char* As1 = lds + 32768;
    char* Bs0 = lds + 65536;
    char* Bs1 = lds + 98304;

    int tid  = threadIdx.x;
    int lane = tid & 63;
    int wv   = tid >> 6;       // 0..7
    int wr   = wv >> 2;        // 0..1  (M-warps)
    int wc   = wv & 3;         // 0..3  (N-warps)

    // T1: XCD-chunked swizzle (512 blocks, %8==0 -> bijective)
    int cpx = gridDim.x >> 3;
    int wid = ((int)blockIdx.x & 7) * cpx + ((int)blockIdx.x >> 3);
    int tn = wid & 3, tm = wid >> 2;   // n fast: same-XCD neighbors share A panel
    int m0 = tm * 256, n0 = tn * 256;

    // B staging source (pre-swizzled Wb -> linear gather)
    const char* srcB = (const char*)B + (((size_t)(n0 + (tid >> 3))) << 11) + ((tid & 7) << 4);

    // A source: raw fp32 x. Thread covers 16 consecutive K-floats of one row
    // per half-tile: row = tid>>2 (+128 for h1), kcols (tid&3)*16 + t*64.
    const float* pA = X + ((size_t)(m0 + (tid >> 2)) << 10) + ((tid & 3) << 4);
    float4 areg[8];

    // A LDS write offsets (swizzled): row*128 + 16*(block ^ (row&7))
    int wrow = tid >> 2;
    int j0   = (tid & 3) << 1;
    int r7   = wrow & 7;
    int aw0  = wrow * 128 + (((j0    ) ^ r7) << 4);
    int aw1  = wrow * 128 + (((j0 + 1) ^ r7) << 4);

    // T2: swizzled ds_read offsets (same involution as writes / Wb pre-swizzle)
    int xr   = (lane & 7) << 4;
    int kq16 = (lane >> 4) << 4;
    int a_off[2], b_off[2];
    {
        int arow = ((wr << 7) + (lane & 15)) << 7;
        int brow = ((wc << 6) + (lane & 15)) << 7;
        a_off[0] = arow + ((kq16 + 0)  ^ xr);
        a_off[1] = arow + ((kq16 + 64) ^ xr);
        b_off[0] = brow + ((kq16 + 0)  ^ xr);
        b_off[1] = brow + ((kq16 + 64) ^ xr);
    }

    f32x4 acc[8][4] = {};

    // ---- prologue ----
    ISSUE_A(0);                                          // 8 vmem
    STAGE_HALF_B(Bs0, 0, 0); STAGE_HALF_B(Bs0, 0, 1);    // +4 = 12
    VMCNT(4);                                            // A(0) regs done
    WRITE_A(As0);
    ISSUE_A(1);                                          // 4+8 = 12
    STAGE_HALF_B(Bs1, 1, 0); STAGE_HALF_B(Bs1, 1, 1);    // 16
    VMCNT(12);                                           // B(0) landed
    LGKM0();                                             // my A(0) ds_writes drained
    PHASE_BAR();

    // ---- main loop: tiles 0..13 ----
    // steady ledger at t.P3 after B-gload: {B(t+1)x4, A(t+1)x8, B(t+2)x4} -> VMCNT(4)
    for (int t = 0; t < NKT - 2; t += 2) {
        KTILE(As0, Bs0,
              { STAGE_HALF_B(Bs0, t + 2, 0); STAGE_HALF_B(Bs0, t + 2, 1);
                VMCNT(4); WRITE_A(As1); },
              { ISSUE_A(t + 2); });
        KTILE(As1, Bs1,
              { STAGE_HALF_B(Bs1, t + 3, 0); STAGE_HALF_B(Bs1, t + 3, 1);
                VMCNT(4); WRITE_A(As0); },
              { ISSUE_A(t + 3); });
    }
    // ---- peeled tiles 14, 15 ----
    KTILE(As0, Bs0, { VMCNT(0); WRITE_A(As1); }, NOHOOK);
    KTILE(As1, Bs1, NOHOOK, NOHOOK);

    // epilogue: C/D layout col = lane&15, row = (lane>>4)*4 + j
    float* Cp = C + ((size_t)(m0 + wr * 128)) * NCH + n0 + wc * 64;
    int cc = lane & 15;
    int rr = (lane >> 4) << 2;
#pragma unroll
    for (int m = 0; m < 8; ++m)
#pragma unroll
        for (int j = 0; j < 4; ++j) {
            float* rowp = Cp + ((size_t)(m * 16 + rr + j)) * NCH;
#pragma unroll
            for (int n = 0; n < 4; ++n)
                rowp[n * 16 + cc] = acc[m][n][j];
        }
}

// ---------------- fallback (ws too small): naive fp32 ----------------
__global__ void naive_kernel(const float* __restrict__ x, const float* __restrict__ w,
                             float* __restrict__ out) {
    int t = blockIdx.x;
    int o = blockIdx.y * 256 + threadIdx.x;
    const float* xr = x + (size_t)t * NCH;
    int r = o >> 6, oi = o & 63;
    float s = 0.f;
    for (int q = 0; q < 16; ++q) {
        const float* wq = w + (r * 16 + q) * 64;
        const float* xq = xr + q * 64;
#pragma unroll 8
        for (int j = 0; j < 64; ++j) s += xq[j] * wq[(oi - j) & 63];
    }
    out[(size_t)t * NCH + o] = s;
}

extern "C" void kernel_launch(void* const* d_in, const int* in_sizes, int n_in,
                              void* d_out, int out_size, void* d_ws, size_t ws_size,
                              hipStream_t stream) {
    const float* x = (const float*)d_in[0];
    const float* w = (const float*)d_in[1];
    float* out = (float*)d_out;

    const size_t needW = (size_t)NCH * NCH * sizeof(unsigned short);   // 2 MB

    if (ws_size >= needW) {
        unsigned short* Wb = (unsigned short*)d_ws;
        hipLaunchKernelGGL(build_w_kernel, dim3(NCH * 128 / 256), dim3(256), 0, stream, w, Wb);
        hipLaunchKernelGGL(gemm8_kernel, dim3(512), dim3(512), 0, stream, x, Wb, out);
    } else {
        hipLaunchKernelGGL(naive_kernel, dim3(NTOK, 4), dim3(256), 0, stream, x, w, out);
    }
}

// Round 4
// 111.418 us; speedup vs baseline: 1.1010x; 1.1010x over previous
//
#include <hip/hip_runtime.h>
#include <stdint.h>

// BCM_Linear: out = x @ W^T, W[o,k] = w[o>>6, k>>6, (o-k)&63]  (1024x1024)
// M=32768, N=1024, K=1024. bf16 MFMA compute, fp32 out.
// Round 4: 128x128 tile, 512 threads, 64KB LDS -> 2 blocks/CU. Cross-block TLP
// hides staging latency + epilogue. Pre-swizzled xb/Wb (T2) + gload_lds linear,
// XCD-chunked grid swizzle (T1), setprio (T5). Simple dbuf 1-bar/K-tile loop.

#define NTOK 32768
#define NCH  1024
#define BK   64
#define NKT  (NCH / BK)   // 16

typedef short bf16x8 __attribute__((ext_vector_type(8)));
typedef float f32x4  __attribute__((ext_vector_type(4)));
typedef unsigned short u16x8 __attribute__((ext_vector_type(8)));

static __device__ __forceinline__ unsigned short f2bf(float f) {
    unsigned int u = __float_as_uint(f);
    u += 0x7FFFu + ((u >> 16) & 1u);
    return (unsigned short)(u >> 16);
}

#define GLOAD16(gp, lp)                                                          \
    __builtin_amdgcn_global_load_lds(                                            \
        (const __attribute__((address_space(1))) unsigned int*)(gp),             \
        (__attribute__((address_space(3))) unsigned int*)(lp), 16, 0, 0)

// ---------------- kernel 1: x fp32 -> bf16, pre-swizzled (round-2 proven) ----------------
__global__ void cvt_x_kernel(const float* __restrict__ x, unsigned short* __restrict__ xb) {
    int i = blockIdx.x * blockDim.x + threadIdx.x;   // 0 .. NTOK*128-1
    int row = i >> 7;
    int j   = i & 127;
    const float4* src = (const float4*)(x + (((size_t)row) << 10) + (j << 3));
    float4 a = src[0], b = src[1];
    u16x8 v;
    v[0]=f2bf(a.x); v[1]=f2bf(a.y); v[2]=f2bf(a.z); v[3]=f2bf(a.w);
    v[4]=f2bf(b.x); v[5]=f2bf(b.y); v[6]=f2bf(b.z); v[7]=f2bf(b.w);
    int js = (j & ~7) | ((j & 7) ^ (row & 7));
    *(u16x8*)(xb + (((size_t)row) << 10) + (js << 3)) = v;
}

// ---------------- kernel 2: circulant w -> dense bf16 W, pre-swizzled (round-2 proven) ----------------
__global__ void build_w_kernel(const float* __restrict__ w, unsigned short* __restrict__ Wb) {
    int i = blockIdx.x * blockDim.x + threadIdx.x;   // 0 .. 1024*128-1
    int o = i >> 7;
    int j = i & 127;
    int r = o >> 6;
    int q = j >> 3;
    const float* wrow = w + ((r * 16 + q) << 6);
    int k0 = j << 3;
    u16x8 v;
#pragma unroll
    for (int e = 0; e < 8; ++e) v[e] = f2bf(wrow[(o - (k0 + e)) & 63]);
    int js = (j & ~7) | ((j & 7) ^ (o & 7));
    *(u16x8*)(Wb + (((size_t)o) << 10) + (js << 3)) = v;
}

// ---------------- kernel 3: 128x128 GEMM, 2 blocks/CU ----------------
#define PHASE_BAR() __builtin_amdgcn_s_barrier()
#define LGKM0() asm volatile("s_waitcnt lgkmcnt(0)" ::: "memory")
#define VMCNT0() asm volatile("s_waitcnt vmcnt(0)" ::: "memory")
#define SETPRIO(n) __builtin_amdgcn_s_setprio(n)
#define MFMA4(d, av, bv) d = __builtin_amdgcn_mfma_f32_16x16x32_bf16(av, bv, d, 0, 0, 0)
#define NOHOOK ((void)0)

// stage full 128x64 A-tile + 128x64 B-tile (16KB each): 4 gload16/thread.
// src rows tid>>3 (+64 for 2nd instr), block tid&7; LDS dest linear wv*1024+lane*16.
#define STAGE(bufA, bufB, t) do {                                                \
    const char* _sa = srcA + ((t) << 7);                                         \
    const char* _sb = srcB + ((t) << 7);                                         \
    char* _da = (bufA) + (wv << 10);                                             \
    char* _db = (bufB) + (wv << 10);                                             \
    GLOAD16(_sa, _da); GLOAD16(_sa + (64 << 11), _da + 8192);                    \
    GLOAD16(_sb, _db); GLOAD16(_sb + (64 << 11), _db + 8192);                    \
} while (0)

// one K-tile: issue stage for a future tile, read frags, MFMA.
#define KSTEP(Abuf, Bbuf, DO_STAGE) do {                                         \
    DO_STAGE;                                                                    \
    bf16x8 afr[4][2], bfr[2][2];                                                 \
    _Pragma("unroll") for (int m = 0; m < 4; ++m)                                \
      _Pragma("unroll") for (int ks = 0; ks < 2; ++ks)                           \
        afr[m][ks] = *(const bf16x8*)((Abuf) + a_off[ks] + m * 2048);            \
    _Pragma("unroll") for (int n = 0; n < 2; ++n)                                \
      _Pragma("unroll") for (int ks = 0; ks < 2; ++ks)                           \
        bfr[n][ks] = *(const bf16x8*)((Bbuf) + b_off[ks] + n * 2048);            \
    LGKM0();                                                                     \
    SETPRIO(1);                                                                  \
    _Pragma("unroll") for (int m = 0; m < 4; ++m)                                \
      _Pragma("unroll") for (int n = 0; n < 2; ++n) {                            \
        MFMA4(acc[m][n], afr[m][0], bfr[n][0]);                                  \
        MFMA4(acc[m][n], afr[m][1], bfr[n][1]);                                  \
      }                                                                          \
    SETPRIO(0);                                                                  \
} while (0)

__global__ void __launch_bounds__(512, 4) gemm128_kernel(const unsigned short* __restrict__ A,
                                                         const unsigned short* __restrict__ B,
                                                         float* __restrict__ C) {
    __shared__ __align__(16) char lds[65536];
    char* As0 = lds;                 // 128 rows x 128 B
    char* As1 = lds + 16384;
    char* Bs0 = lds + 32768;
    char* Bs1 = lds + 49152;

    int tid  = threadIdx.x;
    int lane = tid & 63;
    int wv   = tid >> 6;       // 0..7
    int wr   = wv >> 2;        // 0..1  (M: 2 x 64 rows)
    int wc   = wv & 3;         // 0..3  (N: 4 x 32 cols)

    // T1: XCD-chunked swizzle; 2048 blocks, cpx=256. tn fast -> the 8 blocks
    // sharing one A-panel are consecutive wid -> same XCD -> A L2/L1-hot.
    int cpx = gridDim.x >> 3;
    int wid = ((int)blockIdx.x & 7) * cpx + ((int)blockIdx.x >> 3);
    int tn = wid & 7, tm = wid >> 3;
    int m0 = tm * 128, n0 = tn * 128;

    const char* srcA = (const char*)A + (((size_t)(m0 + (tid >> 3))) << 11) + ((tid & 7) << 4);
    const char* srcB = (const char*)B + (((size_t)(n0 + (tid >> 3))) << 11) + ((tid & 7) << 4);

    // T2 swizzled ds_read offsets. row&7 == lane&7 for all frags (16|rows).
    int xa   = (lane & 7) << 4;
    int kq16 = (lane >> 4) << 4;
    int abase = (wr * 64 + (lane & 15)) * 128;
    int bbase = (wc * 32 + (lane & 15)) * 128;
    int a_off[2] = { abase + (kq16 ^ xa), abase + ((64 + kq16) ^ xa) };
    int b_off[2] = { bbase + (kq16 ^ xa), bbase + ((64 + kq16) ^ xa) };

    f32x4 acc[4][2] = {};

    STAGE(As0, Bs0, 0);
    VMCNT0(); PHASE_BAR();

    for (int t = 0; t < NKT; t += 2) {
        // tile t (bufs 0): stage t+1 into bufs 1 (last read at t-1, 1 bar ago)
        KSTEP(As0, Bs0, STAGE(As1, Bs1, t + 1));
        VMCNT0(); PHASE_BAR();
        if (t + 2 < NKT) {
            KSTEP(As1, Bs1, STAGE(As0, Bs0, t + 2));
            VMCNT0(); PHASE_BAR();
        } else {
            KSTEP(As1, Bs1, NOHOOK);   // last tile, no prefetch
        }
    }

    // epilogue: C/D layout col = lane&15, row = (lane>>4)*4 + j
    float* Cp = C + ((size_t)(m0 + wr * 64)) * NCH + n0 + wc * 32;
    int cc = lane & 15;
    int rr = (lane >> 4) << 2;
#pragma unroll
    for (int m = 0; m < 4; ++m)
#pragma unroll
        for (int j = 0; j < 4; ++j) {
            float* rowp = Cp + ((size_t)(m * 16 + rr + j)) * NCH;
#pragma unroll
            for (int n = 0; n < 2; ++n)
                rowp[n * 16 + cc] = acc[m][n][j];
        }
}

// ---------------- fallback (ws too small): naive fp32 ----------------
__global__ void naive_kernel(const float* __restrict__ x, const float* __restrict__ w,
                             float* __restrict__ out) {
    int t = blockIdx.x;
    int o = blockIdx.y * 256 + threadIdx.x;
    const float* xr = x + (size_t)t * NCH;
    int r = o >> 6, oi = o & 63;
    float s = 0.f;
    for (int q = 0; q < 16; ++q) {
        const float* wq = w + (r * 16 + q) * 64;
        const float* xq = xr + q * 64;
#pragma unroll 8
        for (int j = 0; j < 64; ++j) s += xq[j] * wq[(oi - j) & 63];
    }
    out[(size_t)t * NCH + o] = s;
}

extern "C" void kernel_launch(void* const* d_in, const int* in_sizes, int n_in,
                              void* d_out, int out_size, void* d_ws, size_t ws_size,
                              hipStream_t stream) {
    const float* x = (const float*)d_in[0];
    const float* w = (const float*)d_in[1];
    float* out = (float*)d_out;

    const size_t needX = (size_t)NTOK * NCH * sizeof(unsigned short);  // 64 MB
    const size_t needW = (size_t)NCH * NCH * sizeof(unsigned short);   //  2 MB

    if (ws_size >= needX + needW) {
        unsigned short* xb = (unsigned short*)d_ws;
        unsigned short* Wb = (unsigned short*)((char*)d_ws + needX);
        hipLaunchKernelGGL(cvt_x_kernel, dim3(NTOK * 128 / 256), dim3(256), 0, stream, x, xb);
        hipLaunchKernelGGL(build_w_kernel, dim3(NCH * 128 / 256), dim3(256), 0, stream, w, Wb);
        hipLaunchKernelGGL(gemm128_kernel, dim3(2048), dim3(512), 0, stream, xb, Wb, out);
    } else {
        hipLaunchKernelGGL(naive_kernel, dim3(NTOK, 4), dim3(256), 0, stream, x, w, out);
    }
}